// Round 1
// baseline (484.974 us; speedup 1.0000x reference)
//
#include <hip/hip_runtime.h>

#define TPB 256
#define EPB 32   // elements (batch items) per block; 8 lanes per element

__device__ __forceinline__ float sigm(float x) {
    return __builtin_amdgcn_rcpf(1.0f + __expf(-x));
}
__device__ __forceinline__ float tanh_fast(float x) {
    float e = __expf(-2.0f * x);
    return (1.0f - e) * __builtin_amdgcn_rcpf(1.0f + e);
}

// Layout notes:
//  sW    [3][2][32][16] : Wih padded to Din=16 (layer0 col15 = 0)
//  sWhh  [3][2][32][8]
//  sB    [3][2][32]
//  sWout [160]
//  bufA/bufB [t=10][e=32][16] : layer activations, ping-pong
//  sH    [wave=4][64]         : per-wave h exchange (8 groups x 8 units)
__global__ __launch_bounds__(TPB, 2)
void lstm_kernel(const float* __restrict__ x,
                 const float* __restrict__ Wih0,
                 const float* __restrict__ Wih_rest,
                 const float* __restrict__ Whh,
                 const float* __restrict__ bW,
                 const float* __restrict__ Wout,
                 const float* __restrict__ bout,
                 float* __restrict__ out)
{
    __shared__ __align__(16) float sW[3072];
    __shared__ __align__(16) float sWhh[1536];
    __shared__ __align__(16) float sB[192];
    __shared__ __align__(16) float sWout[160];
    __shared__ __align__(16) float bufA[5120];
    __shared__ __align__(16) float bufB[5120];
    __shared__ __align__(16) float sH[256];

    const int tid = threadIdx.x;

    // ---- stage weights into LDS ----
    for (int i = tid; i < 3072; i += TPB) sW[i] = 0.0f;
    __syncthreads();
    for (int i = tid; i < 960; i += TPB) {            // Wih0 [2][32][15] -> layer0 padded
        int dir = i / 480, r = i % 480, row = r / 15, d = r % 15;
        sW[dir*512 + row*16 + d] = Wih0[i];
    }
    for (int i = tid; i < 2048; i += TPB) {           // Wih_rest [2][2][32][16] contiguous
        int pre = i >> 9;                             // (l-1)*2+dir
        sW[(2 + pre)*512 + (i & 511)] = Wih_rest[i];
    }
    for (int i = tid; i < 1536; i += TPB) sWhh[i] = Whh[i];
    for (int i = tid; i < 192;  i += TPB) sB[i]   = bW[i];
    for (int i = tid; i < 160;  i += TPB) sWout[i] = Wout[i];

    // ---- stage x (coalesced): x[b][c][t][d] -> bufA[t][e][c*5+d] ----
    const float* xblk = x + (size_t)blockIdx.x * (EPB * 150);
    for (int i = tid; i < EPB*150; i += TPB) {
        int e = i / 150, r = i % 150;
        int c = r / 50, r2 = r % 50, t = r2 / 5, d = r2 % 5;
        bufA[(t*EPB + e)*16 + c*5 + d] = xblk[i];
    }
    for (int i = tid; i < 320; i += TPB) {            // zero pad column 15
        int t = i >> 5, e = i & 31;
        bufA[(t*EPB + e)*16 + 15] = 0.0f;
    }
    __syncthreads();

    const int lane = tid & 63;
    const int wid  = tid >> 6;
    const int grp  = lane >> 3;   // element within wave
    const int j    = lane & 7;    // hidden unit owned by this lane
    const int el   = wid*8 + grp; // element within block
    const int w64  = wid*64;

    float* cur = bufA;
    float* nxt = bufB;
    float acc = 0.0f;

    #pragma unroll 1
    for (int l = 0; l < 3; ++l) {
        #pragma unroll 1
        for (int dir = 0; dir < 2; ++dir) {
            const int base = l*2 + dir;
            const float* Wi = &sW[base*512];
            const float* Wh = &sWhh[base*256];
            const float* Bb = &sB[base*32];

            // per-lane weights resident in VGPRs for all 10 steps
            float wih[4][16], whh[4][8], wb[4];
            #pragma unroll
            for (int g = 0; g < 4; ++g) {
                const int row = g*8 + j;
                #pragma unroll
                for (int d4 = 0; d4 < 4; ++d4) {
                    float4 v = *(const float4*)&Wi[row*16 + d4*4];
                    wih[g][d4*4+0] = v.x; wih[g][d4*4+1] = v.y;
                    wih[g][d4*4+2] = v.z; wih[g][d4*4+3] = v.w;
                }
                float4 a  = *(const float4*)&Wh[row*8];
                float4 bq = *(const float4*)&Wh[row*8 + 4];
                whh[g][0]=a.x;  whh[g][1]=a.y;  whh[g][2]=a.z;  whh[g][3]=a.w;
                whh[g][4]=bq.x; whh[g][5]=bq.y; whh[g][6]=bq.z; whh[g][7]=bq.w;
                wb[g] = Bb[row];
            }

            float cst = 0.0f;
            sH[w64 + lane] = 0.0f;   // h0 = 0; same-wave DS ordering guarantees visibility

            #pragma unroll
            for (int tt = 0; tt < 10; ++tt) {
                const int s = dir ? (9 - tt) : tt;
                const float4* xp = (const float4*)&cur[(s*EPB + el)*16];
                float4 x0 = xp[0], x1 = xp[1], x2 = xp[2], x3 = xp[3];
                float xt[16] = {x0.x,x0.y,x0.z,x0.w, x1.x,x1.y,x1.z,x1.w,
                                x2.x,x2.y,x2.z,x2.w, x3.x,x3.y,x3.z,x3.w};
                float4 h0 = *(const float4*)&sH[w64 + grp*8];
                float4 h1 = *(const float4*)&sH[w64 + grp*8 + 4];
                float hk[8] = {h0.x,h0.y,h0.z,h0.w, h1.x,h1.y,h1.z,h1.w};

                float g0 = wb[0], g1 = wb[1], g2 = wb[2], g3 = wb[3];
                #pragma unroll
                for (int d = 0; d < 16; ++d) {
                    g0 += wih[0][d]*xt[d]; g1 += wih[1][d]*xt[d];
                    g2 += wih[2][d]*xt[d]; g3 += wih[3][d]*xt[d];
                }
                #pragma unroll
                for (int k = 0; k < 8; ++k) {
                    g0 += whh[0][k]*hk[k]; g1 += whh[1][k]*hk[k];
                    g2 += whh[2][k]*hk[k]; g3 += whh[3][k]*hk[k];
                }

                const float ig = sigm(g0), fg = sigm(g1);
                const float gg = tanh_fast(g2), og = sigm(g3);
                cst = fg*cst + ig*gg;
                const float hn = og * tanh_fast(cst);

                sH[w64 + lane] = hn;                    // publish h for next step
                if (l < 2) {
                    nxt[(s*EPB + el)*16 + dir*8 + j] = hn;
                } else {
                    acc += hn * sWout[s*16 + dir*8 + j];
                }
            }
        }
        float* tsw = cur; cur = nxt; nxt = tsw;
    }

    // reduce 8 lanes of the group -> scalar output
    acc += __shfl_xor(acc, 1);
    acc += __shfl_xor(acc, 2);
    acc += __shfl_xor(acc, 4);
    if (j == 0) {
        out[(size_t)blockIdx.x * EPB + el] = acc + bout[0];
    }
}

extern "C" void kernel_launch(void* const* d_in, const int* in_sizes, int n_in,
                              void* d_out, int out_size, void* d_ws, size_t ws_size,
                              hipStream_t stream) {
    const float* x        = (const float*)d_in[0];
    const float* Wih0     = (const float*)d_in[1];
    const float* Wih_rest = (const float*)d_in[2];
    const float* Whh      = (const float*)d_in[3];
    const float* b        = (const float*)d_in[4];
    const float* Wout     = (const float*)d_in[5];
    const float* bout     = (const float*)d_in[6];
    float* out = (float*)d_out;

    const int nblocks = out_size / EPB;  // 262144 / 32 = 8192
    lstm_kernel<<<nblocks, TPB, 0, stream>>>(x, Wih0, Wih_rest, Whh, b, Wout, bout, out);
}